// Round 5
// baseline (180.911 us; speedup 1.0000x reference)
//
#include <hip/hip_runtime.h>
#include <hip/hip_bf16.h>
#include <cstdint>
#include <cstddef>

#define IN_DIM 1024
#define OUT_DIM 1024
#define BATCH 2048
#define NSEG 8                    // surviving coefficients per input (m in [5,12])
#define K2 (IN_DIM * NSEG)        // 8192

typedef float f32x4 __attribute__((ext_vector_type(4)));
typedef __bf16 bf16x8 __attribute__((ext_vector_type(8)));

// round-to-nearest-even f32 -> bf16 bits
__device__ __forceinline__ unsigned int f2bf(float f) {
  unsigned int u = __float_as_uint(f);
  u += 0x7FFF + ((u >> 16) & 1);
  return u >> 16;
}

// async global->LDS, 16B per lane (lds dest wave-uniform base + lane*16)
__device__ __forceinline__ void gload16(const void* g, void* l) {
  __builtin_amdgcn_global_load_lds((__attribute__((address_space(1))) void*)g,
                                   (__attribute__((address_space(3))) void*)l,
                                   16, 0, 0);
}

// quadratic B-spline: 8-wide bf16 window (coeff indices m=5..12) for one input.
// 3 nonzero weights at m = j-2..j, placed branchlessly via 128-bit shift.
__device__ __forceinline__ uint4 basis8(float v) {
  float u = (v + 1.125f) * (1.0f / 0.15f);   // knots: -1.125 + m*0.15
  int j = (int)floorf(u);                    // in [7,14] for x in [0,1)
  j = j < 7 ? 7 : (j > 14 ? 14 : j);         // shift-UB guard only
  float s = u - (float)j;
  unsigned long long w0 = f2bf(0.5f * (1.f - s) * (1.f - s));
  unsigned long long w1 = f2bf(0.5f + s * (1.f - s));
  unsigned long long w2 = f2bf(0.5f * s * s);
  unsigned __int128 pack = (unsigned __int128)(w0 | (w1 << 16) | (w2 << 32))
                           << (16 * (j - 7));   // bits >127 drop = coeffs m>12
  unsigned long long lo = (unsigned long long)pack;
  unsigned long long hi = (unsigned long long)(pack >> 64);
  uint4 o;
  o.x = (unsigned int)lo; o.y = (unsigned int)(lo >> 32);
  o.z = (unsigned int)hi; o.w = (unsigned int)(hi >> 32);
  return o;
}

// ---------------------------------------------------------------------------
// silu_init: out[b][:] = w_b * sum_i silu(x[b][i])   (GEMM atomics add splines)
// ---------------------------------------------------------------------------
__global__ __launch_bounds__(256) void silu_init(const float* __restrict__ x,
                                                 float* __restrict__ out,
                                                 const float* __restrict__ wbp) {
  __shared__ float red[4];
  const int b = blockIdx.x;
  const int t = threadIdx.x;
  float4 xv = ((const float4*)(x + (size_t)b * IN_DIM))[t];
  float lsum = xv.x / (1.f + __expf(-xv.x)) + xv.y / (1.f + __expf(-xv.y)) +
               xv.z / (1.f + __expf(-xv.z)) + xv.w / (1.f + __expf(-xv.w));
#pragma unroll
  for (int off = 32; off >= 1; off >>= 1) lsum += __shfl_down(lsum, off);
  if ((t & 63) == 0) red[t >> 6] = lsum;
  __syncthreads();
  float v = wbp[0] * (red[0] + red[1] + red[2] + red[3]);
  float4 vv = {v, v, v, v};
  ((float4*)(out + (size_t)b * OUT_DIM))[t] = vv;
}

// ---------------------------------------------------------------------------
// prep_b: LDS-coalesced repack. Block stages 256 pairs' 13 floats (13312 B)
// via aligned uint4 loads, then each thread gathers its 8 coeffs (5..12) from
// LDS (stride 13 dwords, 13 coprime 32 -> conflict-free), scales by w_s,
// casts to bf16, writes one coalesced uint4.
// ---------------------------------------------------------------------------
__global__ __launch_bounds__(256) void prep_b(const float* __restrict__ p,
                                              short* __restrict__ B,
                                              const float* __restrict__ wsp) {
  __shared__ float ld[3328];          // 256 pairs * 13 floats
  const int blk = blockIdx.x;
  const int t = threadIdx.x;
  const uint4* src = (const uint4*)(p + (size_t)blk * 3328);   // 832 uint4
  uint4* l4 = (uint4*)ld;
#pragma unroll
  for (int c = 0; c < 3; ++c) l4[c * 256 + t] = src[c * 256 + t];
  if (t < 64) l4[768 + t] = src[768 + t];
  __syncthreads();
  const float* my = ld + t * 13 + 5;
  const float w = wsp[0];
  uint4 o;
  o.x = f2bf(w * my[0]) | (f2bf(w * my[1]) << 16);
  o.y = f2bf(w * my[2]) | (f2bf(w * my[3]) << 16);
  o.z = f2bf(w * my[4]) | (f2bf(w * my[5]) << 16);
  o.w = f2bf(w * my[6]) | (f2bf(w * my[7]) << 16);
  ((uint4*)B)[(size_t)blk * 256 + t] = o;
}

// ---------------------------------------------------------------------------
// gemm_fused: out += bases(x)(2048x8192) * B'(1024x8192)^T.
// 64x256 tile, BK=32, 4 waves (each 64x64), TRUE 2-phase double-buffer:
// stage tile t+1 (B global_load_lds + basis ds_write) before computing tile t
// from the other buffer; ONE vmcnt(0)+barrier per K-step. split-K=4 (512
// blocks, 2/CU) + atomic epilogue (w_s folded into B').
// ---------------------------------------------------------------------------
#define BM 64
#define BN 256
#define BK 32
#define KSPLIT 4
#define KPB (K2 / KSPLIT)     // 2048
#define KSTEPS (KPB / BK)     // 64

__global__ __launch_bounds__(256) void gemm_fused(const float* __restrict__ x,
                                                  const short* __restrict__ B,
                                                  float* __restrict__ out) {
  __shared__ __bf16 As[2][BM][BK];   //  8 KB
  __shared__ __bf16 Bs[2][BN][BK];   // 32 KB

  const int tid = threadIdx.x;
  const int wid = tid >> 6;
  const int lane = tid & 63;
  const int bm = blockIdx.x >> 2;   // 32 M-tiles
  const int bn = blockIdx.x & 3;    // 4 N-tiles
  const int ks = blockIdx.y;        // split-K index
  const int row0 = bm * BM;
  const int col0 = bn * BN;
  const int kstart = ks * KPB;
  const int istart = kstart / NSEG; // first input column of this ks slice

  // B staging: wave wid stages rows [64*wid, 64*wid+64), 4 chunks of 16 rows.
  const int sr = lane >> 2;
  const int sc = (lane & 3) * 8;
  const short* bg = B + (size_t)(col0 + 64 * wid + sr) * K2 + kstart + sc;

  // A on-the-fly: thread t owns (row tid>>2, input-in-window tid&3); its uint4
  // lands at slot tid (lane-linear ds_write_b128, conflict-free).
  const float* xp = x + (size_t)(row0 + (tid >> 2)) * IN_DIM + istart + (tid & 3);

  f32x4 acc[4][4];
#pragma unroll
  for (int m = 0; m < 4; ++m)
#pragma unroll
    for (int n = 0; n < 4; ++n) acc[m][n] = (f32x4){0.f, 0.f, 0.f, 0.f};

  const int wc = 64 * wid;          // wave col offset in tile
  const int fr = lane & 15;
  const int fk = (lane >> 4) * 8;

  // ---- prologue: stage tile 0 into buffer 0 ----
  float xv = xp[0];
#pragma unroll
  for (int c = 0; c < 4; ++c)
    gload16(bg + (size_t)(c * 16) * K2, &Bs[0][64 * wid + c * 16][0]);
  ((uint4*)As[0])[tid] = basis8(xv);
  xv = xp[4];                        // x for tile 1
  __syncthreads();                   // (compiler drains vmcnt before barrier)

  int cur = 0;
  for (int kt = 0; kt < KSTEPS; ++kt) {
    // ---- stage tile kt+1 into buffer cur^1 (loads span the MFMA phase) ----
    if (kt + 1 < KSTEPS) {
      const int kb = (kt + 1) * BK;
#pragma unroll
      for (int c = 0; c < 4; ++c)
        gload16(bg + (size_t)(c * 16) * K2 + kb, &Bs[cur ^ 1][64 * wid + c * 16][0]);
      ((uint4*)As[cur ^ 1])[tid] = basis8(xv);
      if (kt + 2 < KSTEPS) xv = xp[(kt + 2) * 4];   // prefetch next x
    }

    // ---- compute tile kt from buffer cur ----
    bf16x8 a[4], bb[4];
#pragma unroll
    for (int m = 0; m < 4; ++m) a[m] = *(const bf16x8*)&As[cur][m * 16 + fr][fk];
#pragma unroll
    for (int n = 0; n < 4; ++n) bb[n] = *(const bf16x8*)&Bs[cur][wc + n * 16 + fr][fk];
#pragma unroll
    for (int m = 0; m < 4; ++m)
#pragma unroll
      for (int n = 0; n < 4; ++n)
        acc[m][n] = __builtin_amdgcn_mfma_f32_16x16x32_bf16(a[m], bb[n], acc[m][n], 0, 0, 0);

    __syncthreads();                 // one vmcnt(0)+barrier per K-step
    cur ^= 1;
  }

  // epilogue: C/D layout col=lane&15, row=(lane>>4)*4+reg (w_s folded into B')
  const int orow = (lane >> 4) * 4;
#pragma unroll
  for (int m = 0; m < 4; ++m)
#pragma unroll
    for (int n = 0; n < 4; ++n) {
      const int rg = row0 + m * 16 + orow;
      const int cg = col0 + wc + n * 16 + fr;
      float* op = out + (size_t)rg * OUT_DIM + cg;
#pragma unroll
      for (int r = 0; r < 4; ++r)
        atomicAdd(op + (size_t)r * OUT_DIM, acc[m][n][r]);
    }
}

// ---------------------------------------------------------------------------
extern "C" void kernel_launch(void* const* d_in, const int* in_sizes, int n_in,
                              void* d_out, int out_size, void* d_ws, size_t ws_size,
                              hipStream_t stream) {
  const float* x = (const float*)d_in[0];     // [2048][1024]
  const float* p = (const float*)d_in[1];     // [1024][1024][13]
  const float* wb = (const float*)d_in[2];    // scalar
  const float* wsc = (const float*)d_in[3];   // scalar
  float* out = (float*)d_out;                 // [2048][1024] fp32

  short* B = (short*)d_ws;                    // B' bf16: 16,777,216 B

  silu_init<<<BATCH, 256, 0, stream>>>(x, out, wb);
  prep_b<<<OUT_DIM * IN_DIM / 256, 256, 0, stream>>>(p, B, wsc);
  dim3 grid(128, KSPLIT);
  gemm_fused<<<grid, 256, 0, stream>>>(x, B, out);
}

// Round 6
// 172.277 us; speedup vs baseline: 1.0501x; 1.0501x over previous
//
#include <hip/hip_runtime.h>
#include <hip/hip_bf16.h>
#include <cstdint>
#include <cstddef>

#define IN_DIM 1024
#define OUT_DIM 1024
#define BATCH 2048
#define NSEG 8                    // surviving coefficients per input (m in [5,12])
#define K2 (IN_DIM * NSEG)        // 8192

typedef float f32x4 __attribute__((ext_vector_type(4)));
typedef __bf16 bf16x8 __attribute__((ext_vector_type(8)));

// round-to-nearest-even f32 -> bf16 bits
__device__ __forceinline__ unsigned int f2bf(float f) {
  unsigned int u = __float_as_uint(f);
  u += 0x7FFF + ((u >> 16) & 1);
  return u >> 16;
}

// async global->LDS, 16B per lane (lds dest wave-uniform base + lane*16)
__device__ __forceinline__ void gload16(const void* g, void* l) {
  __builtin_amdgcn_global_load_lds((__attribute__((address_space(1))) void*)g,
                                   (__attribute__((address_space(3))) void*)l,
                                   16, 0, 0);
}

// quadratic B-spline: 8-wide bf16 window (coeff indices m=5..12) for one input.
__device__ __forceinline__ uint4 basis8(float v) {
  float u = (v + 1.125f) * (1.0f / 0.15f);   // knots: -1.125 + m*0.15
  int j = (int)floorf(u);                    // in [7,14] for x in [0,1)
  j = j < 7 ? 7 : (j > 14 ? 14 : j);         // shift-UB guard only
  float s = u - (float)j;
  unsigned long long w0 = f2bf(0.5f * (1.f - s) * (1.f - s));
  unsigned long long w1 = f2bf(0.5f + s * (1.f - s));
  unsigned long long w2 = f2bf(0.5f * s * s);
  unsigned __int128 pack = (unsigned __int128)(w0 | (w1 << 16) | (w2 << 32))
                           << (16 * (j - 7));   // bits >127 drop = coeffs m>12
  unsigned long long lo = (unsigned long long)pack;
  unsigned long long hi = (unsigned long long)(pack >> 64);
  uint4 o;
  o.x = (unsigned int)lo; o.y = (unsigned int)(lo >> 32);
  o.z = (unsigned int)hi; o.w = (unsigned int)(hi >> 32);
  return o;
}

// ---------------------------------------------------------------------------
// silu_init: out[b][:] = w_b * sum_i silu(x[b][i])   (GEMM atomics add splines)
// ---------------------------------------------------------------------------
__global__ __launch_bounds__(256) void silu_init(const float* __restrict__ x,
                                                 float* __restrict__ out,
                                                 const float* __restrict__ wbp) {
  __shared__ float red[4];
  const int b = blockIdx.x;
  const int t = threadIdx.x;
  float4 xv = ((const float4*)(x + (size_t)b * IN_DIM))[t];
  float lsum = xv.x / (1.f + __expf(-xv.x)) + xv.y / (1.f + __expf(-xv.y)) +
               xv.z / (1.f + __expf(-xv.z)) + xv.w / (1.f + __expf(-xv.w));
#pragma unroll
  for (int off = 32; off >= 1; off >>= 1) lsum += __shfl_down(lsum, off);
  if ((t & 63) == 0) red[t >> 6] = lsum;
  __syncthreads();
  float v = wbp[0] * (red[0] + red[1] + red[2] + red[3]);
  float4 vv = {v, v, v, v};
  ((float4*)(out + (size_t)b * OUT_DIM))[t] = vv;
}

// ---------------------------------------------------------------------------
// prep_b: LDS-coalesced repack of P coeffs 5..12, scaled by w_s, bf16.
// ---------------------------------------------------------------------------
__global__ __launch_bounds__(256) void prep_b(const float* __restrict__ p,
                                              short* __restrict__ B,
                                              const float* __restrict__ wsp) {
  __shared__ float ld[3328];          // 256 pairs * 13 floats
  const int blk = blockIdx.x;
  const int t = threadIdx.x;
  const uint4* src = (const uint4*)(p + (size_t)blk * 3328);   // 832 uint4
  uint4* l4 = (uint4*)ld;
#pragma unroll
  for (int c = 0; c < 3; ++c) l4[c * 256 + t] = src[c * 256 + t];
  if (t < 64) l4[768 + t] = src[768 + t];
  __syncthreads();
  const float* my = ld + t * 13 + 5;
  const float w = wsp[0];
  uint4 o;
  o.x = f2bf(w * my[0]) | (f2bf(w * my[1]) << 16);
  o.y = f2bf(w * my[2]) | (f2bf(w * my[3]) << 16);
  o.z = f2bf(w * my[4]) | (f2bf(w * my[5]) << 16);
  o.w = f2bf(w * my[6]) | (f2bf(w * my[7]) << 16);
  ((uint4*)B)[(size_t)blk * 256 + t] = o;
}

// ---------------------------------------------------------------------------
// gemm_fused: out += bases(x)(2048x8192) * B'(1024x8192)^T.
// 64x256 tile, BK=32, 4 waves (each 64x64). COUNTED-VMCNT pipeline (T4):
//  - each wave reads ONLY the Bs rows it staged itself -> B sync is a per-wave
//    counted s_waitcnt vmcnt(N); no barrier, loads span iterations.
//  - A-tile (cross-wave) syncs via s_waitcnt lgkmcnt(0) + raw s_barrier;
//    vmcnt is NEVER drained at the barrier.
//  - x prefetch depth-2 in parity registers (xa/xb), loop 2x-unrolled so no
//    register rotate waits on an in-flight load. Peeled tail: vmcnt(4)/(0).
// split-K=4 (512 blocks, 2/CU) + atomic epilogue (w_s folded into B').
// ---------------------------------------------------------------------------
#define BM 64
#define BN 256
#define BK 32
#define KSPLIT 4
#define KPB (K2 / KSPLIT)     // 2048
#define KSTEPS (KPB / BK)     // 64

__global__ __launch_bounds__(256) void gemm_fused(const float* __restrict__ x,
                                                  const short* __restrict__ B,
                                                  float* __restrict__ out) {
  __shared__ __bf16 As[2][BM][BK];   //  8 KB
  __shared__ __bf16 Bs[2][BN][BK];   // 32 KB

  const int tid = threadIdx.x;
  const int wid = tid >> 6;
  const int lane = tid & 63;
  const int bm = blockIdx.x >> 2;   // 32 M-tiles
  const int bn = blockIdx.x & 3;    // 4 N-tiles
  const int ks = blockIdx.y;        // split-K index
  const int row0 = bm * BM;
  const int col0 = bn * BN;
  const int kstart = ks * KPB;
  const int istart = kstart / NSEG;

  // B staging: wave wid stages AND consumes rows [64*wid, 64*wid+64)
  const int sr = lane >> 2;
  const int sc = (lane & 3) * 8;
  const short* bg = B + (size_t)(col0 + 64 * wid + sr) * K2 + kstart + sc;

  // A on-the-fly: thread t -> (row t>>2, input t&3); uint4 slot t (lane-linear)
  const float* xp = x + (size_t)(row0 + (tid >> 2)) * IN_DIM + istart + (tid & 3);

  f32x4 acc[4][4];
#pragma unroll
  for (int m = 0; m < 4; ++m)
#pragma unroll
    for (int n = 0; n < 4; ++n) acc[m][n] = (f32x4){0.f, 0.f, 0.f, 0.f};

  const int wc = 64 * wid;
  const int fr = lane & 15;
  const int fk = (lane >> 4) * 8;

#define STAGE_B(kt_, buf_)                                                    \
  {                                                                           \
    const int kb_ = (kt_)*BK;                                                 \
    _Pragma("unroll") for (int c = 0; c < 4; ++c)                             \
        gload16(bg + (size_t)(c * 16) * K2 + kb_,                             \
                &Bs[buf_][64 * wid + c * 16][0]);                             \
  }

#define COMPUTE(buf_)                                                         \
  {                                                                           \
    bf16x8 af[4], bb[4];                                                      \
    _Pragma("unroll") for (int m = 0; m < 4; ++m)                             \
        af[m] = *(const bf16x8*)&As[buf_][m * 16 + fr][fk];                   \
    _Pragma("unroll") for (int n = 0; n < 4; ++n)                             \
        bb[n] = *(const bf16x8*)&Bs[buf_][wc + n * 16 + fr][fk];              \
    _Pragma("unroll") for (int m = 0; m < 4; ++m)                             \
        _Pragma("unroll") for (int n = 0; n < 4; ++n)                         \
            acc[m][n] = __builtin_amdgcn_mfma_f32_16x16x32_bf16(              \
                af[m], bb[n], acc[m][n], 0, 0, 0);                            \
  }

#define LDS_BARRIER                                                           \
  asm volatile("s_waitcnt lgkmcnt(0)" ::: "memory");                          \
  __builtin_amdgcn_s_barrier();

  // ---- prologue: stage tile 0 into buffer 0 ----
  float xa = xp[0];                  // x for even tiles (t0)
  float xb = xp[4];                  // x for odd tiles  (t1)
  STAGE_B(0, 0);
  ((uint4*)As[0])[tid] = basis8(xa);
  LDS_BARRIER;                       // As(0) visible; B(0) still in flight

  // ---- main loop: t = 0..61, 2x-unrolled (31 pairs) ----
#pragma unroll 1
  for (int i = 0; i < (KSTEPS - 2) / 2; ++i) {
    const int t0 = 2 * i;
    // even step t0: stage t0+1 (odd -> uses xb), reload xa = x(t0+2)
    STAGE_B(t0 + 1, 1);
    ((uint4*)As[1])[tid] = basis8(xb);
    xa = xp[(t0 + 2) * 4];
    asm volatile("s_waitcnt vmcnt(5)" ::: "memory");  // B(t0) done; B(t0+1)+x fly
    COMPUTE(0);
    LDS_BARRIER;
    // odd step t0+1: stage t0+2 (even -> uses xa), reload xb = x(t0+3)
    STAGE_B(t0 + 2, 0);
    ((uint4*)As[0])[tid] = basis8(xa);
    xb = xp[(t0 + 3) * 4];
    asm volatile("s_waitcnt vmcnt(5)" ::: "memory");
    COMPUTE(1);
    LDS_BARRIER;
  }

  // ---- peeled tail: t = 62 (stage 63, no x reload), then t = 63 ----
  STAGE_B(KSTEPS - 1, 1);            // tile 63 -> buf 1; uses xb = x(63)
  ((uint4*)As[1])[tid] = basis8(xb);
  asm volatile("s_waitcnt vmcnt(4)" ::: "memory");   // B(62) done
  COMPUTE(0);
  LDS_BARRIER;

  asm volatile("s_waitcnt vmcnt(0)" ::: "memory");   // B(63) done
  COMPUTE(1);

#undef STAGE_B
#undef COMPUTE
#undef LDS_BARRIER

  // epilogue: C/D layout col=lane&15, row=(lane>>4)*4+reg (w_s folded into B')
  const int orow = (lane >> 4) * 4;
#pragma unroll
  for (int m = 0; m < 4; ++m)
#pragma unroll
    for (int n = 0; n < 4; ++n) {
      const int rg = row0 + m * 16 + orow;
      const int cg = col0 + wc + n * 16 + fr;
      float* op = out + (size_t)rg * OUT_DIM + cg;
#pragma unroll
      for (int r = 0; r < 4; ++r)
        atomicAdd(op + (size_t)r * OUT_DIM, acc[m][n][r]);
    }
}

// ---------------------------------------------------------------------------
extern "C" void kernel_launch(void* const* d_in, const int* in_sizes, int n_in,
                              void* d_out, int out_size, void* d_ws, size_t ws_size,
                              hipStream_t stream) {
  const float* x = (const float*)d_in[0];     // [2048][1024]
  const float* p = (const float*)d_in[1];     // [1024][1024][13]
  const float* wb = (const float*)d_in[2];    // scalar
  const float* wsc = (const float*)d_in[3];   // scalar
  float* out = (float*)d_out;                 // [2048][1024] fp32

  short* B = (short*)d_ws;                    // B' bf16: 16,777,216 B

  silu_init<<<BATCH, 256, 0, stream>>>(x, out, wb);
  prep_b<<<OUT_DIM * IN_DIM / 256, 256, 0, stream>>>(p, B, wsc);
  dim3 grid(128, KSPLIT);
  gemm_fused<<<grid, 256, 0, stream>>>(x, B, out);
}